// Round 8
// baseline (327.177 us; speedup 1.0000x reference)
//
#include <hip/hip_runtime.h>
#include <math.h>

typedef __attribute__((ext_vector_type(8))) short bf16x8;
typedef __attribute__((ext_vector_type(4))) float f32x4;
typedef unsigned short ushort_t;

#define SQRT_D 11.313708498984761f
#define INV_SQRT_D 0.08838834764831845f

__device__ __forceinline__ unsigned short f2b(float f) {
    unsigned u = __float_as_uint(f);
    unsigned r = (u + 0x7fffu + ((u >> 16) & 1u)) >> 16;
    return (unsigned short)r;
}
__device__ __forceinline__ float b2f(unsigned short h) {
    return __uint_as_float(((unsigned)h) << 16);
}

__device__ __forceinline__ void async_copy16(const void* g, void* l) {
    __builtin_amdgcn_global_load_lds((const __attribute__((address_space(1))) void*)g,
                                     (__attribute__((address_space(3))) void*)l, 16, 0, 0);
}

// ---------------------------------------------------------------------------
// prep: 64x64 transpose tiles, wide accesses (float4 reads, ushort4 writes).
// grid (32,32,5): z<4 -> transpose W_z; z==4 -> X convert; block (0,0,4) also
// runs splat_prep on its first 128 threads.
// ---------------------------------------------------------------------------
__global__ __launch_bounds__(256) void prep(
    const float* __restrict__ X, const float* __restrict__ W0,
    const float* __restrict__ W1, const float* __restrict__ W2,
    const float* __restrict__ W3, const float* __restrict__ sp,
    const float* __restrict__ sd, const float* __restrict__ ls,
    const float* __restrict__ la, ushort_t* __restrict__ Xbf,
    ushort_t* __restrict__ WT4, float* __restrict__ posn,
    float* __restrict__ dirn, float* __restrict__ pos_sq,
    float* __restrict__ pdv, float* __restrict__ iv2s2,
    float* __restrict__ amp) {
    __shared__ float t[64][65];
    const int z = blockIdx.z;
    const int tid = threadIdx.x;
    if (z < 4) {
        const float* W = (z == 0) ? W0 : (z == 1) ? W1 : (z == 2) ? W2 : W3;
        ushort_t* WT = WT4 + (size_t)z * 4194304;
        const int bn = blockIdx.x * 64, bk = blockIdx.y * 64;
        const int c4 = (tid & 15) * 4;  // 0..60
        const int r0 = tid >> 4;        // 0..15
#pragma unroll
        for (int p = 0; p < 4; ++p) {
            int r = r0 + p * 16;
            float4 v = *(const float4*)(W + (size_t)(bk + r) * 2048 + bn + c4);
            t[r][c4] = v.x; t[r][c4 + 1] = v.y; t[r][c4 + 2] = v.z; t[r][c4 + 3] = v.w;
        }
        __syncthreads();
#pragma unroll
        for (int p = 0; p < 4; ++p) {
            int n = r0 + p * 16;
            ushort4 o;
            o.x = f2b(t[c4][n]);     o.y = f2b(t[c4 + 1][n]);
            o.z = f2b(t[c4 + 2][n]); o.w = f2b(t[c4 + 3][n]);
            *(ushort4*)(WT + (size_t)(bn + n) * 2048 + bk + c4) = o;
        }
        return;
    }
    // convert X: 1024 blocks, 4 x float4 per thread
    {
        int bi = blockIdx.y * 32 + blockIdx.x;
#pragma unroll
        for (int p = 0; p < 4; ++p) {
            int i = (((bi * 4 + p) * 256) + tid) * 4;
            float4 v = *(const float4*)(X + i);
            ushort4 o;
            o.x = f2b(v.x); o.y = f2b(v.y); o.z = f2b(v.z); o.w = f2b(v.w);
            *(ushort4*)(Xbf + i) = o;
        }
    }
    // splat prep (one block only)
    if (blockIdx.x == 0 && blockIdx.y == 0 && tid < 128) {
        int i = tid;
        const float* p = sp + (size_t)i * 128;
        const float* d = sd + (size_t)i * 128;
        float np_ = 0.f, nd_ = 0.f;
        for (int k = 0; k < 128; ++k) { np_ += p[k] * p[k]; nd_ += d[k] * d[k]; }
        np_ = sqrtf(np_); nd_ = sqrtf(nd_);
        const float sc = 3.394112549695428f;  // sqrt(128)*0.3
        float rp = sc / (np_ + 1e-12f);
        float rd = 1.f / (nd_ + 1e-12f);
        float psq = 0.f, pd_ = 0.f;
        for (int k = 0; k < 128; ++k) {
            float pn = p[k] * rp;
            float dn = d[k] * rd;
            posn[(size_t)i * 128 + k] = pn;
            dirn[(size_t)i * 128 + k] = dn;
            psq += pn * pn;
            pd_ += pn * dn;
        }
        pos_sq[i] = psq;
        pdv[i] = pd_;
        float s = expf(ls[i]);
        s = fminf(fmaxf(s, 0.3f), 1.2f);
        iv2s2[i] = 0.5f / (s * s);
        if ((i & 7) == 0) {
            int h = i >> 3;
            float mx = -INFINITY;
            for (int n = 0; n < 8; ++n) mx = fmaxf(mx, la[h * 8 + n]);
            float e[8]; float ssum = 0.f;
            for (int n = 0; n < 8; ++n) { e[n] = expf(la[h * 8 + n] - mx); ssum += e[n]; }
            for (int n = 0; n < 8; ++n) amp[h * 8 + n] = e[n] / ssum;
        }
    }
}

// LDS chunk swizzle (64 B rows, 4x16B chunks): phys = c ^ ((r + (r>>2)) & 3).

// ---------------------------------------------------------------------------
// gemm_qkv: fused Q/K/V projection, grid (16,48) = 768 blocks = 3 blocks/CU.
// which = blockIdx.y>>4. Q scaled by 1/sqrt(D); V also written [b,h,d,s].
// (At the 2-phase structural ceiling ~696 TF; 8-phase ports regressed —
//  1-block/CU killed inter-block TLP. Do not re-attempt without new evidence.)
// ---------------------------------------------------------------------------
__global__ __launch_bounds__(256) void gemm_qkv(const ushort_t* __restrict__ A,
                                                const ushort_t* __restrict__ WT4,
                                                ushort_t* __restrict__ Qb,
                                                ushort_t* __restrict__ Kb,
                                                ushort_t* __restrict__ Vb,
                                                ushort_t* __restrict__ Vt) {
    __shared__ ushort_t As0[128 * 32], As1[128 * 32];
    __shared__ ushort_t Bs0[128 * 32], Bs1[128 * 32];
    const int tid = threadIdx.x, lane = tid & 63, wave = tid >> 6;
    const int l15 = lane & 15, quad = lane >> 4;
    const int wm = (wave >> 1) * 64, wn = (wave & 1) * 64;
    const int bm = blockIdx.x * 128;
    const int by = blockIdx.y, which = by >> 4, bn = (by & 15) * 128;
    const ushort_t* BT = WT4 + (size_t)which * 4194304;
    f32x4 acc[4][4] = {};
    const int off0 = tid * 16;
    const int row0 = tid >> 2;
    const int c0 = (tid & 3) ^ ((row0 + (row0 >> 2)) & 3);
    const ushort_t* ga = A + (size_t)(bm + row0) * 2048 + c0 * 8;
    const ushort_t* gb = BT + (size_t)(bn + row0) * 2048 + c0 * 8;
    const int rsw = (l15 + (l15 >> 2)) & 3;
#define STAGEG(ABUF, BBUF, k_)                                                 \
    {                                                                          \
        async_copy16(ga + (k_), (char*)(ABUF) + off0);                         \
        async_copy16(ga + (size_t)64 * 2048 + (k_), (char*)(ABUF) + off0 + 4096); \
        async_copy16(gb + (k_), (char*)(BBUF) + off0);                         \
        async_copy16(gb + (size_t)64 * 2048 + (k_), (char*)(BBUF) + off0 + 4096); \
    }
#define COMPUTEG(ABUF, BBUF)                                                   \
    {                                                                          \
        bf16x8 af[4], bfr[4];                                                  \
        _Pragma("unroll") for (int i = 0; i < 4; ++i)                          \
            af[i] = *(const bf16x8*)((const char*)(ABUF) + (wm + i * 16 + l15) * 64 + ((quad ^ rsw) << 4)); \
        _Pragma("unroll") for (int j = 0; j < 4; ++j)                          \
            bfr[j] = *(const bf16x8*)((const char*)(BBUF) + (wn + j * 16 + l15) * 64 + ((quad ^ rsw) << 4)); \
        _Pragma("unroll") for (int i = 0; i < 4; ++i)                          \
            _Pragma("unroll") for (int j = 0; j < 4; ++j)                      \
                acc[i][j] = __builtin_amdgcn_mfma_f32_16x16x32_bf16(af[i], bfr[j], acc[i][j], 0, 0, 0); \
    }
    STAGEG(As0, Bs0, 0);
    for (int k0 = 0; k0 < 2048; k0 += 64) {
        __syncthreads();
        STAGEG(As1, Bs1, k0 + 32);
        COMPUTEG(As0, Bs0);
        __syncthreads();
        if (k0 + 64 < 2048) STAGEG(As0, Bs0, k0 + 64);
        COMPUTEG(As1, Bs1);
    }
#undef STAGEG
#undef COMPUTEG
    ushort_t* Cb = (which == 0) ? Qb : ((which == 1) ? Kb : Vb);
    const bool dot = (which == 2);
    const float oscale = (which == 0) ? INV_SQRT_D : 1.f;
#pragma unroll
    for (int i = 0; i < 4; ++i) {
#pragma unroll
        for (int j = 0; j < 4; ++j) {
            int m0 = bm + wm + i * 16 + quad * 4;
            int n = bn + wn + j * 16 + l15;
            int b = m0 >> 10, s0 = m0 & 1023, h = n >> 7, d = n & 127;
            ushort4 pack;
            unsigned short* pp = (unsigned short*)&pack;
#pragma unroll
            for (int r = 0; r < 4; ++r) {
                unsigned short bv = f2b(acc[i][j][r] * oscale);
                pp[r] = bv;
                Cb[((size_t)((b << 4) | h) * 1024 + (s0 + r)) * 128 + d] = bv;
            }
            if (dot) *(ushort4*)(Vt + ((size_t)((b << 4) | h) * 128 + d) * 1024 + s0) = pack;
        }
    }
}

// ---------------------------------------------------------------------------
// gemm_out (r8): reverted to the r0 128x64 tile, grid (16,32) = 512 blocks
// = 2 blocks/CU. Isolating r2->r3 showed the 128x128/1-block-per-CU widening
// likely cost ~5 us (third measurement of the same 1-block/CU TLP loss).
// ---------------------------------------------------------------------------
__global__ __launch_bounds__(256) void gemm_out(const ushort_t* __restrict__ A,
                                                const ushort_t* __restrict__ BT,
                                                float* __restrict__ Cf) {
    __shared__ ushort_t As0[128 * 32], As1[128 * 32];
    __shared__ ushort_t Bs0[64 * 32], Bs1[64 * 32];
    const int tid = threadIdx.x, lane = tid & 63, wave = tid >> 6;
    const int l15 = lane & 15, quad = lane >> 4;
    const int wm = (wave >> 1) * 64, wn = (wave & 1) * 32;
    const int bm = blockIdx.x * 128, bn = blockIdx.y * 64;
    f32x4 acc[4][2] = {};
    const int off0 = tid * 16;
    const int row0 = tid >> 2;
    const int c0 = (tid & 3) ^ ((row0 + (row0 >> 2)) & 3);
    const ushort_t* ga = A + (size_t)(bm + row0) * 2048 + c0 * 8;
    const ushort_t* gb = BT + (size_t)(bn + row0) * 2048 + c0 * 8;
    const int rsw = (l15 + (l15 >> 2)) & 3;
#define STAGEO(ABUF, BBUF, k_)                                                 \
    {                                                                          \
        async_copy16(ga + (k_), (char*)(ABUF) + off0);                         \
        async_copy16(ga + (size_t)64 * 2048 + (k_), (char*)(ABUF) + off0 + 4096); \
        async_copy16(gb + (k_), (char*)(BBUF) + off0);                         \
    }
#define COMPUTEO(ABUF, BBUF)                                                   \
    {                                                                          \
        bf16x8 af[4], bfr[2];                                                  \
        _Pragma("unroll") for (int i = 0; i < 4; ++i)                          \
            af[i] = *(const bf16x8*)((const char*)(ABUF) + (wm + i * 16 + l15) * 64 + ((quad ^ rsw) << 4)); \
        _Pragma("unroll") for (int j = 0; j < 2; ++j)                          \
            bfr[j] = *(const bf16x8*)((const char*)(BBUF) + (wn + j * 16 + l15) * 64 + ((quad ^ rsw) << 4)); \
        _Pragma("unroll") for (int i = 0; i < 4; ++i)                          \
            _Pragma("unroll") for (int j = 0; j < 2; ++j)                      \
                acc[i][j] = __builtin_amdgcn_mfma_f32_16x16x32_bf16(af[i], bfr[j], acc[i][j], 0, 0, 0); \
    }
    STAGEO(As0, Bs0, 0);
    for (int k0 = 0; k0 < 2048; k0 += 64) {
        __syncthreads();
        STAGEO(As1, Bs1, k0 + 32);
        COMPUTEO(As0, Bs0);
        __syncthreads();
        if (k0 + 64 < 2048) STAGEO(As0, Bs0, k0 + 64);
        COMPUTEO(As1, Bs1);
    }
#undef STAGEO
#undef COMPUTEO
#pragma unroll
    for (int i = 0; i < 4; ++i)
#pragma unroll
        for (int j = 0; j < 2; ++j)
#pragma unroll
            for (int r = 0; r < 4; ++r) {
                int m = bm + wm + i * 16 + quad * 4 + r;
                int n = bn + wn + j * 16 + l15;
                Cf[(size_t)m * 2048 + n] = acc[i][j][r];
            }
}

// ---------------------------------------------------------------------------
// kv_s1_part: FUSED ka-affinity + partial KV/S1 over a 64-row S-chunk.
// grid (32 bh, 16 sc), 128 threads.
// Phase A: ALL 128 threads (2 per token, 64-d halves), partials via LDS.
// Phase B: thread (n=tid>>4, d8=tid&15) owns KV[n][d8*8..+8]; vector V loads.
// ---------------------------------------------------------------------------
__global__ __launch_bounds__(128) void kv_s1_part(
    const ushort_t* __restrict__ K, const ushort_t* __restrict__ V,
    const float* __restrict__ posn, const float* __restrict__ dirn,
    const float* __restrict__ pos_sq, const float* __restrict__ pdv,
    const float* __restrict__ iv2s2, const float* __restrict__ ds_in,
    float* __restrict__ KVp, float* __restrict__ S1p) {
    __shared__ float parts[128][17];
    __shared__ float kas[64][8];
    const int bh = blockIdx.x, sc = blockIdx.y;
    const int tid = threadIdx.x;
    const int h = bh & 15;
    // Phase A: 2 threads per token, 64 d each
    {
        const int tk = tid & 63, half = tid >> 6;
        const ushort_t* T = K + ((size_t)bh * 1024 + sc * 64 + tk) * 128 + half * 64;
        const float* Pb = posn + (size_t)(h * 8) * 128 + half * 64;
        const float* Db = dirn + (size_t)(h * 8) * 128 + half * 64;
        float tsq = 0.f, tp[8] = {}, td[8] = {};
        for (int d = 0; d < 64; d += 4) {
            uint2 raw = *(const uint2*)(T + d);
            float t0 = __uint_as_float(raw.x << 16), t1 = __uint_as_float(raw.x & 0xffff0000u);
            float t2 = __uint_as_float(raw.y << 16), t3 = __uint_as_float(raw.y & 0xffff0000u);
            tsq += t0 * t0 + t1 * t1 + t2 * t2 + t3 * t3;
#pragma unroll
            for (int n = 0; n < 8; ++n) {
                float4 p = *(const float4*)(Pb + (size_t)n * 128 + d);
                float4 e = *(const float4*)(Db + (size_t)n * 128 + d);
                tp[n] += t0 * p.x + t1 * p.y + t2 * p.z + t3 * p.w;
                td[n] += t0 * e.x + t1 * e.y + t2 * e.z + t3 * e.w;
            }
        }
        parts[tid][0] = tsq;
#pragma unroll
        for (int n = 0; n < 8; ++n) { parts[tid][1 + n] = tp[n]; parts[tid][9 + n] = td[n]; }
    }
    __syncthreads();
    if (tid < 64) {
        float dsv = 1.f / (1.f + __expf(-ds_in[0]));
        float tsq = parts[tid][0] + parts[tid + 64][0];
#pragma unroll
        for (int n = 0; n < 8; ++n) {
            float tp = parts[tid][1 + n] + parts[tid + 64][1 + n];
            float td = parts[tid][9 + n] + parts[tid + 64][9 + n];
            float dist2 = fmaxf(tsq - 2.f * tp + pos_sq[h * 8 + n], 0.f);
            float proj = td - pdv[h * 8 + n];
            float perp2 = fmaxf(dist2 - proj * proj, 0.f);
            float iv = iv2s2[h * 8 + n];
            kas[tid][n] = (1.f - dsv) * __expf(-dist2 * iv) + dsv * __expf(-perp2 * iv);
        }
    }
    __syncthreads();
    // Phase B: thread (n, d8) accumulates over all 64 s with vector V loads
    {
        const int n = tid >> 4, d8 = tid & 15;
        const ushort_t* VB = V + ((size_t)bh * 1024 + sc * 64) * 128 + d8 * 8;
        f32x4 a0 = {}, a1 = {};
        float s1 = 0.f;
#pragma unroll 4
        for (int s = 0; s < 64; ++s) {
            bf16x8 v8 = *(const bf16x8*)(VB + (size_t)s * 128);
            float ka = kas[s][n];
            s1 += ka;
            a0[0] += ka * b2f((unsigned short)v8[0]);
            a0[1] += ka * b2f((unsigned short)v8[1]);
            a0[2] += ka * b2f((unsigned short)v8[2]);
            a0[3] += ka * b2f((unsigned short)v8[3]);
            a1[0] += ka * b2f((unsigned short)v8[4]);
            a1[1] += ka * b2f((unsigned short)v8[5]);
            a1[2] += ka * b2f((unsigned short)v8[6]);
            a1[3] += ka * b2f((unsigned short)v8[7]);
        }
        float* outp = KVp + (((size_t)bh * 8 + n) * 16 + sc) * 128 + d8 * 8;
        *(f32x4*)outp = a0;
        *(f32x4*)(outp + 4) = a1;
        if (d8 == 0) S1p[((size_t)bh * 8 + n) * 16 + sc] = s1;
    }
}

// ---------------------------------------------------------------------------
// flash_blend: affinity fused in; staged K/V dbuf; r8 adds s_setprio(1)
// around both MFMA clusters (T5; attn-proven +4-7%, may be null here).
// grid (16 qt, 32 bh), 256 threads.
// ---------------------------------------------------------------------------
__global__ __launch_bounds__(256) void flash_blend(
    const ushort_t* __restrict__ Qg, const ushort_t* __restrict__ Kg,
    const ushort_t* __restrict__ Vtg,
    const float* __restrict__ posn, const float* __restrict__ dirn,
    const float* __restrict__ pos_sq, const float* __restrict__ pdv,
    const float* __restrict__ iv2s2, const float* __restrict__ dstr,
    const float* __restrict__ amp,
    const float* __restrict__ S1p, const float* __restrict__ KVp,
    const float* __restrict__ gstr, ushort_t* __restrict__ blended) {
    __shared__ ushort_t Ks0[64 * 128], Ks1[64 * 128];  // [key][d], swizzled ^(key&15)
    __shared__ ushort_t Vt0[128 * 64], Vt1[128 * 64];  // [d][key], swizzled ^(d&7)
    __shared__ ushort_t Ps[4][16 * 72];                // wave-private P
    __shared__ float KVs[8 * 128];
    __shared__ float S1s[8];
    __shared__ float qas[4][16][8];                    // wave-private q-affinity
    const int tid = threadIdx.x, lane = tid & 63, wave = tid >> 6;
    const int l15 = lane & 15, quad = lane >> 4;
    const int bh = blockIdx.y, qt = blockIdx.x;
    const int h = bh & 15;

    const ushort_t* Qrow = Qg + ((size_t)(bh * 1024 + qt * 64 + wave * 16 + l15)) * 128 + quad * 8;
    bf16x8 aq[4];
#pragma unroll
    for (int k4 = 0; k4 < 4; ++k4) aq[k4] = *(const bf16x8*)(Qrow + k4 * 32);

    // ---- fused q-affinity (was affinity_q kernel) ----
    {
        const float dsv = 1.f / (1.f + __expf(-dstr[0]));
        float tsq = 0.f, tp[8] = {}, td[8] = {};
#pragma unroll
        for (int k4 = 0; k4 < 4; ++k4) {
            float tv[8];
#pragma unroll
            for (int j = 0; j < 8; ++j) tv[j] = b2f((unsigned short)aq[k4][j]);
            const int d0 = k4 * 32 + quad * 8;
#pragma unroll
            for (int j = 0; j < 8; ++j) tsq += tv[j] * tv[j];
#pragma unroll
            for (int n = 0; n < 8; ++n) {
                const float* P = posn + (size_t)(h * 8 + n) * 128 + d0;
                const float* Dr = dirn + (size_t)(h * 8 + n) * 128 + d0;
                float4 p0 = *(const float4*)P, p1 = *(const float4*)(P + 4);
                float4 e0 = *(const float4*)Dr, e1 = *(const float4*)(Dr + 4);
                tp[n] += tv[0] * p0.x + tv[1] * p0.y + tv[2] * p0.z + tv[3] * p0.w
                       + tv[4] * p1.x + tv[5] * p1.y + tv[6] * p1.z + tv[7] * p1.w;
                td[n] += tv[0] * e0.x + tv[1] * e0.y + tv[2] * e0.z + tv[3] * e0.w
                       + tv[4] * e1.x + tv[5] * e1.y + tv[6] * e1.z + tv[7] * e1.w;
            }
        }
        tsq += __shfl_xor(tsq, 16); tsq += __shfl_xor(tsq, 32);
#pragma unroll
        for (int n = 0; n < 8; ++n) {
            tp[n] += __shfl_xor(tp[n], 16); tp[n] += __shfl_xor(tp[n], 32);
            td[n] += __shfl_xor(td[n], 16); td[n] += __shfl_xor(td[n], 32);
        }
        if (quad == 0) {
            const float fs = SQRT_D;  // undo 1/sqrt(D) prescale on Q
            float ts = tsq * fs * fs;
#pragma unroll
            for (int n = 0; n < 8; ++n) {
                float tpn = tp[n] * fs, tdn = td[n] * fs;
                float dist2 = fmaxf(ts - 2.f * tpn + pos_sq[h * 8 + n], 0.f);
                float proj = tdn - pdv[h * 8 + n];
                float perp2 = fmaxf(dist2 - proj * proj, 0.f);
                float iv = iv2s2[h * 8 + n];
                qas[wave][l15][n] = (1.f - dsv) * __expf(-dist2 * iv) + dsv * __expf(-perp2 * iv);
            }
        }
    }

    {
        int n = tid >> 5, d = (tid & 31) * 4;
        f32x4 kv = {};
#pragma unroll
        for (int sc = 0; sc < 16; ++sc)
            kv += *(const f32x4*)(KVp + (((size_t)bh * 8 + n) * 16 + sc) * 128 + d);
        *(f32x4*)(KVs + tid * 4) = kv;
    }
    if (tid < 8) {
        float s = 0.f;
#pragma unroll
        for (int sc = 0; sc < 16; ++sc) s += S1p[((size_t)bh * 8 + tid) * 16 + sc];
        S1s[tid] = s;
    }

    const ushort_t* Kbase = Kg + (size_t)bh * 131072;
    const ushort_t* Vbase = Vtg + (size_t)bh * 131072;

#define STAGE(KBUF, VBUF, kt_)                                                        \
    {                                                                                 \
        _Pragma("unroll") for (int i_ = 0; i_ < 4; ++i_) {                            \
            int off_ = tid * 16 + i_ * 4096;                                          \
            int kr_ = off_ >> 8, kp_ = (off_ >> 4) & 15;                              \
            async_copy16(Kbase + (size_t)(kt_)*8192 + kr_ * 128 + ((kp_ ^ (kr_ & 15)) << 3), \
                         (char*)(KBUF) + off_);                                       \
            int vd_ = off_ >> 7, vp_ = (off_ >> 4) & 7;                               \
            async_copy16(Vbase + (size_t)vd_ * 1024 + (kt_)*64 + ((vp_ ^ (vd_ & 7)) << 3), \
                         (char*)(VBUF) + off_);                                       \
        }                                                                             \
    }
#define FLASH_STEP(KBUF, VBUF)                                                        \
    {                                                                                 \
        f32x4 sc[4] = {};                                                             \
        __builtin_amdgcn_s_setprio(1);                                                \
        _Pragma("unroll") for (int k4 = 0; k4 < 4; ++k4) {                            \
            _Pragma("unroll") for (int t = 0; t < 4; ++t) {                           \
                bf16x8 bk = *(const bf16x8*)((const char*)(KBUF) +                    \
                                             ((t * 16 + l15) << 8) + (((k4 * 4 + quad) ^ l15) << 4)); \
                sc[t] = __builtin_amdgcn_mfma_f32_16x16x32_bf16(aq[k4], bk, sc[t], 0, 0, 0); \
            }                                                                         \
        }                                                                             \
        __builtin_amdgcn_s_setprio(0);                                                \
        _Pragma("unroll") for (int t = 0; t < 4; ++t) {                               \
            _Pragma("unroll") for (int r = 0; r < 4; ++r) {                           \
                float p = __expf(sc[t][r]);                                           \
                l_i[r] += p;                                                          \
                Pw[(quad * 4 + r) * 72 + t * 16 + l15] = f2b(p);                      \
            }                                                                         \
        }                                                                             \
        bf16x8 ap0 = *(const bf16x8*)((const char*)Pw + (l15 * 72 + quad * 8) * 2);   \
        bf16x8 ap1 = *(const bf16x8*)((const char*)Pw + (l15 * 72 + 32 + quad * 8) * 2); \
        __builtin_amdgcn_s_setprio(1);                                                \
        _Pragma("unroll") for (int j = 0; j < 8; ++j) {                               \
            bf16x8 bv0 = *(const bf16x8*)((const char*)(VBUF) +                       \
                                          ((j * 16 + l15) << 7) + (((quad) ^ (l15 & 7)) << 4)); \
            bf16x8 bv1 = *(const bf16x8*)((const char*)(VBUF) +                       \
                                          ((j * 16 + l15) << 7) + (((4 + quad) ^ (l15 & 7)) << 4)); \
            o[j] = __builtin_amdgcn_mfma_f32_16x16x32_bf16(ap0, bv0, o[j], 0, 0, 0);  \
            o[j] = __builtin_amdgcn_mfma_f32_16x16x32_bf16(ap1, bv1, o[j], 0, 0, 0);  \
        }                                                                             \
        __builtin_amdgcn_s_setprio(0);                                                \
    }

    STAGE(Ks0, Vt0, 0);

    f32x4 o[8] = {};
    float l_i[4] = {};
    ushort_t* Pw = &Ps[wave][0];

    for (int kt = 0; kt < 16; kt += 2) {
        __syncthreads();
        STAGE(Ks1, Vt1, kt + 1);
        FLASH_STEP(Ks0, Vt0);
        __syncthreads();
        if (kt + 2 < 16) STAGE(Ks0, Vt0, kt + 2);
        FLASH_STEP(Ks1, Vt1);
    }
#undef STAGE
#undef FLASH_STEP
#pragma unroll
    for (int r = 0; r < 4; ++r) {
        float l = l_i[r];
        l += __shfl_xor(l, 1);
        l += __shfl_xor(l, 2);
        l += __shfl_xor(l, 4);
        l += __shfl_xor(l, 8);
        l_i[r] = l;
    }
    float gsa = 1.f / (1.f + __expf(-gstr[0]));
    float blend = fminf(0.05f, gsa * 0.1f);
    int b = bh >> 4;
#pragma unroll
    for (int r = 0; r < 4; ++r) {
        int q = qt * 64 + wave * 16 + quad * 4 + r;
        const float* qaRow = &qas[wave][quad * 4 + r][0];
        float qam[8], Z = 0.f;
#pragma unroll
        for (int n = 0; n < 8; ++n) {
            qam[n] = qaRow[n] * amp[h * 8 + n];
            Z += qam[n] * S1s[n];
        }
        float invZ = 1.f / (Z + 1e-8f);
        float invl = 1.f / l_i[r];
        ushort_t* outp = blended + ((size_t)(b * 1024 + q)) * 2048 + h * 128;
#pragma unroll
        for (int j = 0; j < 8; ++j) {
            int d = j * 16 + l15;
            float dg = 0.f;
#pragma unroll
            for (int n = 0; n < 8; ++n) dg += qam[n] * KVs[n * 128 + d];
            float v = (1.f - blend) * (o[j][r] * invl) + blend * (dg * invZ);
            outp[d] = f2b(v);
        }
    }
}

// ---------------------------------------------------------------------------
extern "C" void kernel_launch(void* const* d_in, const int* in_sizes, int n_in,
                              void* d_out, int out_size, void* d_ws, size_t ws_size,
                              hipStream_t stream) {
    const float* X = (const float*)d_in[0];
    const float* Wq = (const float*)d_in[1];
    const float* Wk = (const float*)d_in[2];
    const float* Wv = (const float*)d_in[3];
    const float* Wo = (const float*)d_in[4];
    const float* sp = (const float*)d_in[5];
    const float* sd = (const float*)d_in[6];
    const float* ls = (const float*)d_in[7];
    const float* la = (const float*)d_in[8];
    const float* dstr = (const float*)d_in[9];
    const float* gstr = (const float*)d_in[10];

    char* base = (char*)d_ws;
    ushort_t* WT4 = (ushort_t*)base;      base += 33554432;  // 4 x 2048^2 bf16
    ushort_t* Xbf = (ushort_t*)base;      base += 8388608;   // overlaid: blended
    ushort_t* blended = Xbf;                                 // Xbf dead after gemm_qkv
    ushort_t* Qbf = (ushort_t*)base;      base += 8388608;
    ushort_t* Kbf = (ushort_t*)base;      base += 8388608;
    ushort_t* Vbf = (ushort_t*)base;      base += 8388608;
    ushort_t* Vtb = (ushort_t*)base;      base += 8388608;
    float* posn = (float*)base;           base += 65536;
    float* dirn = (float*)base;           base += 65536;
    float* pos_sq = (float*)base;         base += 512;
    float* pdv = (float*)base;            base += 512;
    float* iv2s2 = (float*)base;          base += 512;
    float* ampw = (float*)base;           base += 512;
    float* S1p = (float*)base;            base += 16384;     // 32*8*16 fp32
    float* KVp = (float*)base;            base += 2097152;   // 32*8*16*128 fp32

    prep<<<dim3(32, 32, 5), 256, 0, stream>>>(X, Wq, Wk, Wv, Wo, sp, sd, ls, la,
                                              Xbf, WT4, posn, dirn, pos_sq, pdv, iv2s2, ampw);
    gemm_qkv<<<dim3(16, 48), 256, 0, stream>>>(Xbf, WT4, Qbf, Kbf, Vbf, Vtb);
    kv_s1_part<<<dim3(32, 16), 128, 0, stream>>>(Kbf, Vbf, posn, dirn, pos_sq, pdv, iv2s2,
                                                 dstr, KVp, S1p);
    flash_blend<<<dim3(16, 32), 256, 0, stream>>>(Qbf, Kbf, Vtb, posn, dirn, pos_sq, pdv,
                                                  iv2s2, dstr, ampw, S1p, KVp, gstr, blended);
    gemm_out<<<dim3(16, 32), 256, 0, stream>>>(blended, WT4 + 12582912, (float*)d_out);
}

// Round 9
// 319.102 us; speedup vs baseline: 1.0253x; 1.0253x over previous
//
#include <hip/hip_runtime.h>
#include <math.h>

typedef __attribute__((ext_vector_type(8))) short bf16x8;
typedef __attribute__((ext_vector_type(4))) float f32x4;
typedef unsigned short ushort_t;

#define SQRT_D 11.313708498984761f
#define INV_SQRT_D 0.08838834764831845f

__device__ __forceinline__ unsigned short f2b(float f) {
    unsigned u = __float_as_uint(f);
    unsigned r = (u + 0x7fffu + ((u >> 16) & 1u)) >> 16;
    return (unsigned short)r;
}
__device__ __forceinline__ float b2f(unsigned short h) {
    return __uint_as_float(((unsigned)h) << 16);
}

__device__ __forceinline__ void async_copy16(const void* g, void* l) {
    __builtin_amdgcn_global_load_lds((const __attribute__((address_space(1))) void*)g,
                                     (__attribute__((address_space(3))) void*)l, 16, 0, 0);
}

// ---------------------------------------------------------------------------
// prep: 64x64 transpose tiles, wide accesses (float4 reads, ushort4 writes).
// grid (32,32,5): z<4 -> transpose W_z; z==4 -> X convert; block (0,0,4) also
// runs splat_prep on its first 128 threads.
// ---------------------------------------------------------------------------
__global__ __launch_bounds__(256) void prep(
    const float* __restrict__ X, const float* __restrict__ W0,
    const float* __restrict__ W1, const float* __restrict__ W2,
    const float* __restrict__ W3, const float* __restrict__ sp,
    const float* __restrict__ sd, const float* __restrict__ ls,
    const float* __restrict__ la, ushort_t* __restrict__ Xbf,
    ushort_t* __restrict__ WT4, float* __restrict__ posn,
    float* __restrict__ dirn, float* __restrict__ pos_sq,
    float* __restrict__ pdv, float* __restrict__ iv2s2,
    float* __restrict__ amp) {
    __shared__ float t[64][65];
    const int z = blockIdx.z;
    const int tid = threadIdx.x;
    if (z < 4) {
        const float* W = (z == 0) ? W0 : (z == 1) ? W1 : (z == 2) ? W2 : W3;
        ushort_t* WT = WT4 + (size_t)z * 4194304;
        const int bn = blockIdx.x * 64, bk = blockIdx.y * 64;
        const int c4 = (tid & 15) * 4;  // 0..60
        const int r0 = tid >> 4;        // 0..15
#pragma unroll
        for (int p = 0; p < 4; ++p) {
            int r = r0 + p * 16;
            float4 v = *(const float4*)(W + (size_t)(bk + r) * 2048 + bn + c4);
            t[r][c4] = v.x; t[r][c4 + 1] = v.y; t[r][c4 + 2] = v.z; t[r][c4 + 3] = v.w;
        }
        __syncthreads();
#pragma unroll
        for (int p = 0; p < 4; ++p) {
            int n = r0 + p * 16;
            ushort4 o;
            o.x = f2b(t[c4][n]);     o.y = f2b(t[c4 + 1][n]);
            o.z = f2b(t[c4 + 2][n]); o.w = f2b(t[c4 + 3][n]);
            *(ushort4*)(WT + (size_t)(bn + n) * 2048 + bk + c4) = o;
        }
        return;
    }
    // convert X: 1024 blocks, 4 x float4 per thread
    {
        int bi = blockIdx.y * 32 + blockIdx.x;
#pragma unroll
        for (int p = 0; p < 4; ++p) {
            int i = (((bi * 4 + p) * 256) + tid) * 4;
            float4 v = *(const float4*)(X + i);
            ushort4 o;
            o.x = f2b(v.x); o.y = f2b(v.y); o.z = f2b(v.z); o.w = f2b(v.w);
            *(ushort4*)(Xbf + i) = o;
        }
    }
    // splat prep (one block only)
    if (blockIdx.x == 0 && blockIdx.y == 0 && tid < 128) {
        int i = tid;
        const float* p = sp + (size_t)i * 128;
        const float* d = sd + (size_t)i * 128;
        float np_ = 0.f, nd_ = 0.f;
        for (int k = 0; k < 128; ++k) { np_ += p[k] * p[k]; nd_ += d[k] * d[k]; }
        np_ = sqrtf(np_); nd_ = sqrtf(nd_);
        const float sc = 3.394112549695428f;  // sqrt(128)*0.3
        float rp = sc / (np_ + 1e-12f);
        float rd = 1.f / (nd_ + 1e-12f);
        float psq = 0.f, pd_ = 0.f;
        for (int k = 0; k < 128; ++k) {
            float pn = p[k] * rp;
            float dn = d[k] * rd;
            posn[(size_t)i * 128 + k] = pn;
            dirn[(size_t)i * 128 + k] = dn;
            psq += pn * pn;
            pd_ += pn * dn;
        }
        pos_sq[i] = psq;
        pdv[i] = pd_;
        float s = expf(ls[i]);
        s = fminf(fmaxf(s, 0.3f), 1.2f);
        iv2s2[i] = 0.5f / (s * s);
        if ((i & 7) == 0) {
            int h = i >> 3;
            float mx = -INFINITY;
            for (int n = 0; n < 8; ++n) mx = fmaxf(mx, la[h * 8 + n]);
            float e[8]; float ssum = 0.f;
            for (int n = 0; n < 8; ++n) { e[n] = expf(la[h * 8 + n] - mx); ssum += e[n]; }
            for (int n = 0; n < 8; ++n) amp[h * 8 + n] = e[n] / ssum;
        }
    }
}

// LDS chunk swizzle (64 B rows, 4x16B chunks): phys = c ^ ((r + (r>>2)) & 3).

// ---------------------------------------------------------------------------
// gemm_qkv: fused Q/K/V projection, grid (16,48) = 768 blocks = 3 blocks/CU.
// which = blockIdx.y>>4. Q scaled by 1/sqrt(D); V also written [b,h,d,s].
// (At the 2-phase structural ceiling ~696 TF; 8-phase ports regressed —
//  1-block/CU killed inter-block TLP. Do not re-attempt without new evidence.)
// ---------------------------------------------------------------------------
__global__ __launch_bounds__(256) void gemm_qkv(const ushort_t* __restrict__ A,
                                                const ushort_t* __restrict__ WT4,
                                                ushort_t* __restrict__ Qb,
                                                ushort_t* __restrict__ Kb,
                                                ushort_t* __restrict__ Vb,
                                                ushort_t* __restrict__ Vt) {
    __shared__ ushort_t As0[128 * 32], As1[128 * 32];
    __shared__ ushort_t Bs0[128 * 32], Bs1[128 * 32];
    const int tid = threadIdx.x, lane = tid & 63, wave = tid >> 6;
    const int l15 = lane & 15, quad = lane >> 4;
    const int wm = (wave >> 1) * 64, wn = (wave & 1) * 64;
    const int bm = blockIdx.x * 128;
    const int by = blockIdx.y, which = by >> 4, bn = (by & 15) * 128;
    const ushort_t* BT = WT4 + (size_t)which * 4194304;
    f32x4 acc[4][4] = {};
    const int off0 = tid * 16;
    const int row0 = tid >> 2;
    const int c0 = (tid & 3) ^ ((row0 + (row0 >> 2)) & 3);
    const ushort_t* ga = A + (size_t)(bm + row0) * 2048 + c0 * 8;
    const ushort_t* gb = BT + (size_t)(bn + row0) * 2048 + c0 * 8;
    const int rsw = (l15 + (l15 >> 2)) & 3;
#define STAGEG(ABUF, BBUF, k_)                                                 \
    {                                                                          \
        async_copy16(ga + (k_), (char*)(ABUF) + off0);                         \
        async_copy16(ga + (size_t)64 * 2048 + (k_), (char*)(ABUF) + off0 + 4096); \
        async_copy16(gb + (k_), (char*)(BBUF) + off0);                         \
        async_copy16(gb + (size_t)64 * 2048 + (k_), (char*)(BBUF) + off0 + 4096); \
    }
#define COMPUTEG(ABUF, BBUF)                                                   \
    {                                                                          \
        bf16x8 af[4], bfr[4];                                                  \
        _Pragma("unroll") for (int i = 0; i < 4; ++i)                          \
            af[i] = *(const bf16x8*)((const char*)(ABUF) + (wm + i * 16 + l15) * 64 + ((quad ^ rsw) << 4)); \
        _Pragma("unroll") for (int j = 0; j < 4; ++j)                          \
            bfr[j] = *(const bf16x8*)((const char*)(BBUF) + (wn + j * 16 + l15) * 64 + ((quad ^ rsw) << 4)); \
        _Pragma("unroll") for (int i = 0; i < 4; ++i)                          \
            _Pragma("unroll") for (int j = 0; j < 4; ++j)                      \
                acc[i][j] = __builtin_amdgcn_mfma_f32_16x16x32_bf16(af[i], bfr[j], acc[i][j], 0, 0, 0); \
    }
    STAGEG(As0, Bs0, 0);
    for (int k0 = 0; k0 < 2048; k0 += 64) {
        __syncthreads();
        STAGEG(As1, Bs1, k0 + 32);
        COMPUTEG(As0, Bs0);
        __syncthreads();
        if (k0 + 64 < 2048) STAGEG(As0, Bs0, k0 + 64);
        COMPUTEG(As1, Bs1);
    }
#undef STAGEG
#undef COMPUTEG
    ushort_t* Cb = (which == 0) ? Qb : ((which == 1) ? Kb : Vb);
    const bool dot = (which == 2);
    const float oscale = (which == 0) ? INV_SQRT_D : 1.f;
#pragma unroll
    for (int i = 0; i < 4; ++i) {
#pragma unroll
        for (int j = 0; j < 4; ++j) {
            int m0 = bm + wm + i * 16 + quad * 4;
            int n = bn + wn + j * 16 + l15;
            int b = m0 >> 10, s0 = m0 & 1023, h = n >> 7, d = n & 127;
            ushort4 pack;
            unsigned short* pp = (unsigned short*)&pack;
#pragma unroll
            for (int r = 0; r < 4; ++r) {
                unsigned short bv = f2b(acc[i][j][r] * oscale);
                pp[r] = bv;
                Cb[((size_t)((b << 4) | h) * 1024 + (s0 + r)) * 128 + d] = bv;
            }
            if (dot) *(ushort4*)(Vt + ((size_t)((b << 4) | h) * 128 + d) * 1024 + s0) = pack;
        }
    }
}

// ---------------------------------------------------------------------------
// gemm_out: C(fp32) = A(bf16) @ BT^T. 128x128 tile, 2-phase dbuf.
// grid (16,16). (r9: restored — r8's 128x64 revert was -3 us net; the r3
// ledger residual I'd attributed to this kernel was noise.)
// ---------------------------------------------------------------------------
__global__ __launch_bounds__(256) void gemm_out(const ushort_t* __restrict__ A,
                                                const ushort_t* __restrict__ BT,
                                                float* __restrict__ Cf) {
    __shared__ ushort_t As0[128 * 32], As1[128 * 32];
    __shared__ ushort_t Bs0[128 * 32], Bs1[128 * 32];
    const int tid = threadIdx.x, lane = tid & 63, wave = tid >> 6;
    const int l15 = lane & 15, quad = lane >> 4;
    const int wm = (wave >> 1) * 64, wn = (wave & 1) * 64;
    const int bm = blockIdx.x * 128, bn = blockIdx.y * 128;
    f32x4 acc[4][4] = {};
    const int off0 = tid * 16;
    const int row0 = tid >> 2;
    const int c0 = (tid & 3) ^ ((row0 + (row0 >> 2)) & 3);
    const ushort_t* ga = A + (size_t)(bm + row0) * 2048 + c0 * 8;
    const ushort_t* gb = BT + (size_t)(bn + row0) * 2048 + c0 * 8;
    const int rsw = (l15 + (l15 >> 2)) & 3;
#define STAGEO(ABUF, BBUF, k_)                                                 \
    {                                                                          \
        async_copy16(ga + (k_), (char*)(ABUF) + off0);                         \
        async_copy16(ga + (size_t)64 * 2048 + (k_), (char*)(ABUF) + off0 + 4096); \
        async_copy16(gb + (k_), (char*)(BBUF) + off0);                         \
        async_copy16(gb + (size_t)64 * 2048 + (k_), (char*)(BBUF) + off0 + 4096); \
    }
#define COMPUTEO(ABUF, BBUF)                                                   \
    {                                                                          \
        bf16x8 af[4], bfr[4];                                                  \
        _Pragma("unroll") for (int i = 0; i < 4; ++i)                          \
            af[i] = *(const bf16x8*)((const char*)(ABUF) + (wm + i * 16 + l15) * 64 + ((quad ^ rsw) << 4)); \
        _Pragma("unroll") for (int j = 0; j < 4; ++j)                          \
            bfr[j] = *(const bf16x8*)((const char*)(BBUF) + (wn + j * 16 + l15) * 64 + ((quad ^ rsw) << 4)); \
        _Pragma("unroll") for (int i = 0; i < 4; ++i)                          \
            _Pragma("unroll") for (int j = 0; j < 4; ++j)                      \
                acc[i][j] = __builtin_amdgcn_mfma_f32_16x16x32_bf16(af[i], bfr[j], acc[i][j], 0, 0, 0); \
    }
    STAGEO(As0, Bs0, 0);
    for (int k0 = 0; k0 < 2048; k0 += 64) {
        __syncthreads();
        STAGEO(As1, Bs1, k0 + 32);
        COMPUTEO(As0, Bs0);
        __syncthreads();
        if (k0 + 64 < 2048) STAGEO(As0, Bs0, k0 + 64);
        COMPUTEO(As1, Bs1);
    }
#undef STAGEO
#undef COMPUTEO
#pragma unroll
    for (int i = 0; i < 4; ++i)
#pragma unroll
        for (int j = 0; j < 4; ++j)
#pragma unroll
            for (int r = 0; r < 4; ++r) {
                int m = bm + wm + i * 16 + quad * 4 + r;
                int n = bn + wn + j * 16 + l15;
                Cf[(size_t)m * 2048 + n] = acc[i][j][r];
            }
}

// ---------------------------------------------------------------------------
// kv_s1_part: FUSED ka-affinity + partial KV/S1 over a 64-row S-chunk.
// grid (32 bh, 16 sc), 128 threads.
// Phase A: ALL 128 threads (2 per token, 64-d halves), partials via LDS.
// Phase B: thread (n=tid>>4, d8=tid&15) owns KV[n][d8*8..+8]; vector V loads.
// ---------------------------------------------------------------------------
__global__ __launch_bounds__(128) void kv_s1_part(
    const ushort_t* __restrict__ K, const ushort_t* __restrict__ V,
    const float* __restrict__ posn, const float* __restrict__ dirn,
    const float* __restrict__ pos_sq, const float* __restrict__ pdv,
    const float* __restrict__ iv2s2, const float* __restrict__ ds_in,
    float* __restrict__ KVp, float* __restrict__ S1p) {
    __shared__ float parts[128][17];
    __shared__ float kas[64][8];
    const int bh = blockIdx.x, sc = blockIdx.y;
    const int tid = threadIdx.x;
    const int h = bh & 15;
    // Phase A: 2 threads per token, 64 d each
    {
        const int tk = tid & 63, half = tid >> 6;
        const ushort_t* T = K + ((size_t)bh * 1024 + sc * 64 + tk) * 128 + half * 64;
        const float* Pb = posn + (size_t)(h * 8) * 128 + half * 64;
        const float* Db = dirn + (size_t)(h * 8) * 128 + half * 64;
        float tsq = 0.f, tp[8] = {}, td[8] = {};
        for (int d = 0; d < 64; d += 4) {
            uint2 raw = *(const uint2*)(T + d);
            float t0 = __uint_as_float(raw.x << 16), t1 = __uint_as_float(raw.x & 0xffff0000u);
            float t2 = __uint_as_float(raw.y << 16), t3 = __uint_as_float(raw.y & 0xffff0000u);
            tsq += t0 * t0 + t1 * t1 + t2 * t2 + t3 * t3;
#pragma unroll
            for (int n = 0; n < 8; ++n) {
                float4 p = *(const float4*)(Pb + (size_t)n * 128 + d);
                float4 e = *(const float4*)(Db + (size_t)n * 128 + d);
                tp[n] += t0 * p.x + t1 * p.y + t2 * p.z + t3 * p.w;
                td[n] += t0 * e.x + t1 * e.y + t2 * e.z + t3 * e.w;
            }
        }
        parts[tid][0] = tsq;
#pragma unroll
        for (int n = 0; n < 8; ++n) { parts[tid][1 + n] = tp[n]; parts[tid][9 + n] = td[n]; }
    }
    __syncthreads();
    if (tid < 64) {
        float dsv = 1.f / (1.f + __expf(-ds_in[0]));
        float tsq = parts[tid][0] + parts[tid + 64][0];
#pragma unroll
        for (int n = 0; n < 8; ++n) {
            float tp = parts[tid][1 + n] + parts[tid + 64][1 + n];
            float td = parts[tid][9 + n] + parts[tid + 64][9 + n];
            float dist2 = fmaxf(tsq - 2.f * tp + pos_sq[h * 8 + n], 0.f);
            float proj = td - pdv[h * 8 + n];
            float perp2 = fmaxf(dist2 - proj * proj, 0.f);
            float iv = iv2s2[h * 8 + n];
            kas[tid][n] = (1.f - dsv) * __expf(-dist2 * iv) + dsv * __expf(-perp2 * iv);
        }
    }
    __syncthreads();
    // Phase B: thread (n, d8) accumulates over all 64 s with vector V loads
    {
        const int n = tid >> 4, d8 = tid & 15;
        const ushort_t* VB = V + ((size_t)bh * 1024 + sc * 64) * 128 + d8 * 8;
        f32x4 a0 = {}, a1 = {};
        float s1 = 0.f;
#pragma unroll 4
        for (int s = 0; s < 64; ++s) {
            bf16x8 v8 = *(const bf16x8*)(VB + (size_t)s * 128);
            float ka = kas[s][n];
            s1 += ka;
            a0[0] += ka * b2f((unsigned short)v8[0]);
            a0[1] += ka * b2f((unsigned short)v8[1]);
            a0[2] += ka * b2f((unsigned short)v8[2]);
            a0[3] += ka * b2f((unsigned short)v8[3]);
            a1[0] += ka * b2f((unsigned short)v8[4]);
            a1[1] += ka * b2f((unsigned short)v8[5]);
            a1[2] += ka * b2f((unsigned short)v8[6]);
            a1[3] += ka * b2f((unsigned short)v8[7]);
        }
        float* outp = KVp + (((size_t)bh * 8 + n) * 16 + sc) * 128 + d8 * 8;
        *(f32x4*)outp = a0;
        *(f32x4*)(outp + 4) = a1;
        if (d8 == 0) S1p[((size_t)bh * 8 + n) * 16 + sc] = s1;
    }
}

// ---------------------------------------------------------------------------
// flash_blend: affinity fused in; staged K/V dbuf (staging-free was 142 us —
// LDS staging IS the latency hider). NO setprio (r8 measured it null-to-
// negative here: lockstep barrier-synced waves = the m190 GEMM null case).
// grid (16 qt, 32 bh), 256 threads.
// ---------------------------------------------------------------------------
__global__ __launch_bounds__(256) void flash_blend(
    const ushort_t* __restrict__ Qg, const ushort_t* __restrict__ Kg,
    const ushort_t* __restrict__ Vtg,
    const float* __restrict__ posn, const float* __restrict__ dirn,
    const float* __restrict__ pos_sq, const float* __restrict__ pdv,
    const float* __restrict__ iv2s2, const float* __restrict__ dstr,
    const float* __restrict__ amp,
    const float* __restrict__ S1p, const float* __restrict__ KVp,
    const float* __restrict__ gstr, ushort_t* __restrict__ blended) {
    __shared__ ushort_t Ks0[64 * 128], Ks1[64 * 128];  // [key][d], swizzled ^(key&15)
    __shared__ ushort_t Vt0[128 * 64], Vt1[128 * 64];  // [d][key], swizzled ^(d&7)
    __shared__ ushort_t Ps[4][16 * 72];                // wave-private P
    __shared__ float KVs[8 * 128];
    __shared__ float S1s[8];
    __shared__ float qas[4][16][8];                    // wave-private q-affinity
    const int tid = threadIdx.x, lane = tid & 63, wave = tid >> 6;
    const int l15 = lane & 15, quad = lane >> 4;
    const int bh = blockIdx.y, qt = blockIdx.x;
    const int h = bh & 15;

    const ushort_t* Qrow = Qg + ((size_t)(bh * 1024 + qt * 64 + wave * 16 + l15)) * 128 + quad * 8;
    bf16x8 aq[4];
#pragma unroll
    for (int k4 = 0; k4 < 4; ++k4) aq[k4] = *(const bf16x8*)(Qrow + k4 * 32);

    // ---- fused q-affinity (was affinity_q kernel) ----
    {
        const float dsv = 1.f / (1.f + __expf(-dstr[0]));
        float tsq = 0.f, tp[8] = {}, td[8] = {};
#pragma unroll
        for (int k4 = 0; k4 < 4; ++k4) {
            float tv[8];
#pragma unroll
            for (int j = 0; j < 8; ++j) tv[j] = b2f((unsigned short)aq[k4][j]);
            const int d0 = k4 * 32 + quad * 8;
#pragma unroll
            for (int j = 0; j < 8; ++j) tsq += tv[j] * tv[j];
#pragma unroll
            for (int n = 0; n < 8; ++n) {
                const float* P = posn + (size_t)(h * 8 + n) * 128 + d0;
                const float* Dr = dirn + (size_t)(h * 8 + n) * 128 + d0;
                float4 p0 = *(const float4*)P, p1 = *(const float4*)(P + 4);
                float4 e0 = *(const float4*)Dr, e1 = *(const float4*)(Dr + 4);
                tp[n] += tv[0] * p0.x + tv[1] * p0.y + tv[2] * p0.z + tv[3] * p0.w
                       + tv[4] * p1.x + tv[5] * p1.y + tv[6] * p1.z + tv[7] * p1.w;
                td[n] += tv[0] * e0.x + tv[1] * e0.y + tv[2] * e0.z + tv[3] * e0.w
                       + tv[4] * e1.x + tv[5] * e1.y + tv[6] * e1.z + tv[7] * e1.w;
            }
        }
        tsq += __shfl_xor(tsq, 16); tsq += __shfl_xor(tsq, 32);
#pragma unroll
        for (int n = 0; n < 8; ++n) {
            tp[n] += __shfl_xor(tp[n], 16); tp[n] += __shfl_xor(tp[n], 32);
            td[n] += __shfl_xor(td[n], 16); td[n] += __shfl_xor(td[n], 32);
        }
        if (quad == 0) {
            const float fs = SQRT_D;  // undo 1/sqrt(D) prescale on Q
            float ts = tsq * fs * fs;
#pragma unroll
            for (int n = 0; n < 8; ++n) {
                float tpn = tp[n] * fs, tdn = td[n] * fs;
                float dist2 = fmaxf(ts - 2.f * tpn + pos_sq[h * 8 + n], 0.f);
                float proj = tdn - pdv[h * 8 + n];
                float perp2 = fmaxf(dist2 - proj * proj, 0.f);
                float iv = iv2s2[h * 8 + n];
                qas[wave][l15][n] = (1.f - dsv) * __expf(-dist2 * iv) + dsv * __expf(-perp2 * iv);
            }
        }
    }

    {
        int n = tid >> 5, d = (tid & 31) * 4;
        f32x4 kv = {};
#pragma unroll
        for (int sc = 0; sc < 16; ++sc)
            kv += *(const f32x4*)(KVp + (((size_t)bh * 8 + n) * 16 + sc) * 128 + d);
        *(f32x4*)(KVs + tid * 4) = kv;
    }
    if (tid < 8) {
        float s = 0.f;
#pragma unroll
        for (int sc = 0; sc < 16; ++sc) s += S1p[((size_t)bh * 8 + tid) * 16 + sc];
        S1s[tid] = s;
    }

    const ushort_t* Kbase = Kg + (size_t)bh * 131072;
    const ushort_t* Vbase = Vtg + (size_t)bh * 131072;

#define STAGE(KBUF, VBUF, kt_)                                                        \
    {                                                                                 \
        _Pragma("unroll") for (int i_ = 0; i_ < 4; ++i_) {                            \
            int off_ = tid * 16 + i_ * 4096;                                          \
            int kr_ = off_ >> 8, kp_ = (off_ >> 4) & 15;                              \
            async_copy16(Kbase + (size_t)(kt_)*8192 + kr_ * 128 + ((kp_ ^ (kr_ & 15)) << 3), \
                         (char*)(KBUF) + off_);                                       \
            int vd_ = off_ >> 7, vp_ = (off_ >> 4) & 7;                               \
            async_copy16(Vbase + (size_t)vd_ * 1024 + (kt_)*64 + ((vp_ ^ (vd_ & 7)) << 3), \
                         (char*)(VBUF) + off_);                                       \
        }                                                                             \
    }
#define FLASH_STEP(KBUF, VBUF)                                                        \
    {                                                                                 \
        f32x4 sc[4] = {};                                                             \
        _Pragma("unroll") for (int k4 = 0; k4 < 4; ++k4) {                            \
            _Pragma("unroll") for (int t = 0; t < 4; ++t) {                           \
                bf16x8 bk = *(const bf16x8*)((const char*)(KBUF) +                    \
                                             ((t * 16 + l15) << 8) + (((k4 * 4 + quad) ^ l15) << 4)); \
                sc[t] = __builtin_amdgcn_mfma_f32_16x16x32_bf16(aq[k4], bk, sc[t], 0, 0, 0); \
            }                                                                         \
        }                                                                             \
        _Pragma("unroll") for (int t = 0; t < 4; ++t) {                               \
            _Pragma("unroll") for (int r = 0; r < 4; ++r) {                           \
                float p = __expf(sc[t][r]);                                           \
                l_i[r] += p;                                                          \
                Pw[(quad * 4 + r) * 72 + t * 16 + l15] = f2b(p);                      \
            }                                                                         \
        }                                                                             \
        bf16x8 ap0 = *(const bf16x8*)((const char*)Pw + (l15 * 72 + quad * 8) * 2);   \
        bf16x8 ap1 = *(const bf16x8*)((const char*)Pw + (l15 * 72 + 32 + quad * 8) * 2); \
        _Pragma("unroll") for (int j = 0; j < 8; ++j) {                               \
            bf16x8 bv0 = *(const bf16x8*)((const char*)(VBUF) +                       \
                                          ((j * 16 + l15) << 7) + (((quad) ^ (l15 & 7)) << 4)); \
            bf16x8 bv1 = *(const bf16x8*)((const char*)(VBUF) +                       \
                                          ((j * 16 + l15) << 7) + (((4 + quad) ^ (l15 & 7)) << 4)); \
            o[j] = __builtin_amdgcn_mfma_f32_16x16x32_bf16(ap0, bv0, o[j], 0, 0, 0);  \
            o[j] = __builtin_amdgcn_mfma_f32_16x16x32_bf16(ap1, bv1, o[j], 0, 0, 0);  \
        }                                                                             \
    }

    STAGE(Ks0, Vt0, 0);

    f32x4 o[8] = {};
    float l_i[4] = {};
    ushort_t* Pw = &Ps[wave][0];

    for (int kt = 0; kt < 16; kt += 2) {
        __syncthreads();
        STAGE(Ks1, Vt1, kt + 1);
        FLASH_STEP(Ks0, Vt0);
        __syncthreads();
        if (kt + 2 < 16) STAGE(Ks0, Vt0, kt + 2);
        FLASH_STEP(Ks1, Vt1);
    }
#undef STAGE
#undef FLASH_STEP
#pragma unroll
    for (int r = 0; r < 4; ++r) {
        float l = l_i[r];
        l += __shfl_xor(l, 1);
        l += __shfl_xor(l, 2);
        l += __shfl_xor(l, 4);
        l += __shfl_xor(l, 8);
        l_i[r] = l;
    }
    float gsa = 1.f / (1.f + __expf(-gstr[0]));
    float blend = fminf(0.05f, gsa * 0.1f);
    int b = bh >> 4;
#pragma unroll
    for (int r = 0; r < 4; ++r) {
        int q = qt * 64 + wave * 16 + quad * 4 + r;
        const float* qaRow = &qas[wave][quad * 4 + r][0];
        float qam[8], Z = 0.f;
#pragma unroll
        for (int n = 0; n < 8; ++n) {
            qam[n] = qaRow[n] * amp[h * 8 + n];
            Z += qam[n] * S1s[n];
        }
        float invZ = 1.f / (Z + 1e-8f);
        float invl = 1.f / l_i[r];
        ushort_t* outp = blended + ((size_t)(b * 1024 + q)) * 2048 + h * 128;
#pragma unroll
        for (int j = 0; j < 8; ++j) {
            int d = j * 16 + l15;
            float dg = 0.f;
#pragma unroll
            for (int n = 0; n < 8; ++n) dg += qam[n] * KVs[n * 128 + d];
            float v = (1.f - blend) * (o[j][r] * invl) + blend * (dg * invZ);
            outp[d] = f2b(v);
        }
    }
}

// ---------------------------------------------------------------------------
extern "C" void kernel_launch(void* const* d_in, const int* in_sizes, int n_in,
                              void* d_out, int out_size, void* d_ws, size_t ws_size,
                              hipStream_t stream) {
    const float* X = (const float*)d_in[0];
    const float* Wq = (const float*)d_in[1];
    const float* Wk = (const float*)d_in[2];
    const float* Wv = (const float*)d_in[3];
    const float* Wo = (const float*)d_in[4];
    const float* sp = (const float*)d_in[5];
    const float* sd = (const float*)d_in[6];
    const float* ls = (const float*)d_in[7];
    const float* la = (const float*)d_in[8];
    const float* dstr = (const float*)d_in[9];
    const float* gstr = (const float*)d_in[10];

    char* base = (char*)d_ws;
    ushort_t* WT4 = (ushort_t*)base;      base += 33554432;  // 4 x 2048^2 bf16
    ushort_t* Xbf = (ushort_t*)base;      base += 8388608;   // overlaid: blended
    ushort_t* blended = Xbf;                                 // Xbf dead after gemm_qkv
    ushort_t* Qbf = (ushort_t*)base;      base += 8388608;
    ushort_t* Kbf = (ushort_t*)base;      base += 8388608;
    ushort_t* Vbf = (ushort_t*)base;      base += 8388608;
    ushort_t* Vtb = (ushort_t*)base;      base += 8388608;
    float* posn = (float*)base;           base += 65536;
    float* dirn = (float*)base;           base += 65536;
    float* pos_sq = (float*)base;         base += 512;
    float* pdv = (float*)base;            base += 512;
    float* iv2s2 = (float*)base;          base += 512;
    float* ampw = (float*)base;           base += 512;
    float* S1p = (float*)base;            base += 16384;     // 32*8*16 fp32
    float* KVp = (float*)base;            base += 2097152;   // 32*8*16*128 fp32

    prep<<<dim3(32, 32, 5), 256, 0, stream>>>(X, Wq, Wk, Wv, Wo, sp, sd, ls, la,
                                              Xbf, WT4, posn, dirn, pos_sq, pdv, iv2s2, ampw);
    gemm_qkv<<<dim3(16, 48), 256, 0, stream>>>(Xbf, WT4, Qbf, Kbf, Vbf, Vtb);
    kv_s1_part<<<dim3(32, 16), 128, 0, stream>>>(Kbf, Vbf, posn, dirn, pos_sq, pdv, iv2s2,
                                                 dstr, KVp, S1p);
    flash_blend<<<dim3(16, 32), 256, 0, stream>>>(Qbf, Kbf, Vtb, posn, dirn, pos_sq, pdv,
                                                  iv2s2, dstr, ampw, S1p, KVp, gstr, blended);
    gemm_out<<<dim3(16, 16), 256, 0, stream>>>(blended, WT4 + 12582912, (float*)d_out);
}